// Round 4
// baseline (56.787 us; speedup 1.0000x reference)
//
#include <hip/hip_runtime.h>

// Deformable depthwise conv1d (fp32), MI355X.
// Round 4: 4 independent outputs/thread (stride-256 -> all LDS lane-stride-1,
// conflict-free), __launch_bounds__(256,8) to pin VGPR<=64 (occupancy cliff),
// v_fract_f32 for bilinear fraction. Targets dependency stalls (both pipes
// were ~72% busy with no single saturated resource).

constexpr int B_ = 8;
constexpr int C_ = 512;
constexpr int T_ = 4096;
constexpr int K_ = 7;
constexpr int T_OUT = T_ - K_ + 1;      // 4090
constexpr int BLOCK = 256;
constexpr int P_ = 16;                  // zero pad each side (>> max |offset|)
constexpr int ROWP = P_ + T_ + P_;      // 4128 floats = 16.5 KB
constexpr int NOUT = 4;                 // outputs per thread per iter
constexpr int SPAN = NOUT * BLOCK;      // 1024 t per outer iter

typedef float v2f __attribute__((ext_vector_type(2)));

__device__ __forceinline__ float fract_pos(float p) {
#if __has_builtin(__builtin_amdgcn_fractf)
    return __builtin_amdgcn_fractf(p);      // v_fract_f32 (p >= 0 here)
#else
    return p - floorf(p);
#endif
}

__global__ __launch_bounds__(BLOCK, 8)
void deform_dwconv1d_kernel(const float* __restrict__ x,
                            const float* __restrict__ weight,
                            const float* __restrict__ offset_w,
                            const float* __restrict__ offset_b,
                            float* __restrict__ out)
{
    __shared__ float rowp[ROWP];

    const int bc  = blockIdx.x;        // b*C + c
    const int c   = bc & (C_ - 1);
    const int tid = threadIdx.x;

    // zero the pads
    if (tid < P_) {
        rowp[tid] = 0.0f;
        rowp[P_ + T_ + tid] = 0.0f;
    }

    // stage x[b,c,:] into rowp[P_ ..] (float4, coalesced)
    const float4* src = reinterpret_cast<const float4*>(x + (size_t)bc * T_);
    float4* dst = reinterpret_cast<float4*>(rowp + P_);
    #pragma unroll
    for (int i = 0; i < T_ / 4 / BLOCK; ++i)   // 4 iters
        dst[tid + i * BLOCK] = src[tid + i * BLOCK];

    // per-channel weights: uniform addresses -> scalar loads / SGPRs
    float ow[K_ * K_];
    #pragma unroll
    for (int i = 0; i < K_ * K_; ++i) ow[i] = offset_w[c * K_ * K_ + i];
    float wgt[K_], obk[K_];
    #pragma unroll
    for (int k = 0; k < K_; ++k) {
        wgt[k] = weight[c * K_ + k];
        obk[k] = offset_b[c * K_ + k] + (float)k;   // fold +k into the bias
    }

    __syncthreads();

    float* orow = out + (size_t)bc * T_OUT;
    constexpr float HI = (float)(ROWP - 2);   // 4126: rowp[HI..HI+1] are pad zeros

    #pragma unroll
    for (int it = 0; it < 4; ++it) {
        const int t0 = it * SPAN + tid;            // all four lane-stride-1

        // 4 windows (conflict-free; pairs fuse to ds_read2_b32)
        float w0[K_], w1[K_], w2[K_], w3[K_];
        #pragma unroll
        for (int j = 0; j < K_; ++j) {
            w0[j] = rowp[P_ + t0 + j];
            w1[j] = rowp[P_ + t0 + 256 + j];
            w2[j] = rowp[P_ + t0 + 512 + j];
            w3[j] = rowp[P_ + t0 + 768 + j];
        }

        const v2f tf01 = {(float)(t0 + P_),       (float)(t0 + 256 + P_)};
        const v2f tf23 = {(float)(t0 + 512 + P_), (float)(t0 + 768 + P_)};
        float acc0 = 0.0f, acc1 = 0.0f, acc2 = 0.0f, acc3 = 0.0f;

        #pragma unroll
        for (int k = 0; k < K_; ++k) {
            // packed offset conv; accumulators seeded with bias + k + t + P
            v2f o01 = tf01 + obk[k];
            v2f o23 = tf23 + obk[k];
            #pragma unroll
            for (int j = 0; j < K_; ++j) {
                const float m = ow[k * K_ + j];
                const v2f mm  = {m, m};
                const v2f a01 = {w0[j], w1[j]};
                const v2f a23 = {w2[j], w3[j]};
                o01 = __builtin_elementwise_fma(a01, mm, o01);
                o23 = __builtin_elementwise_fma(a23, mm, o23);
            }

            const float wk = wgt[k];

            // 4 independent samples: clamp (v_med3) -> trunc/fract -> ds_read2
            {
                const float p = fminf(fmaxf(o01.x, 0.0f), HI);
                const int   i0 = (int)p;
                const float u  = fract_pos(p);
                const float g0 = rowp[i0], g1 = rowp[i0 + 1];
                acc0 = fmaf(fmaf(u, g1 - g0, g0), wk, acc0);
            }
            {
                const float p = fminf(fmaxf(o01.y, 0.0f), HI);
                const int   i0 = (int)p;
                const float u  = fract_pos(p);
                const float g0 = rowp[i0], g1 = rowp[i0 + 1];
                acc1 = fmaf(fmaf(u, g1 - g0, g0), wk, acc1);
            }
            {
                const float p = fminf(fmaxf(o23.x, 0.0f), HI);
                const int   i0 = (int)p;
                const float u  = fract_pos(p);
                const float g0 = rowp[i0], g1 = rowp[i0 + 1];
                acc2 = fmaf(fmaf(u, g1 - g0, g0), wk, acc2);
            }
            {
                const float p = fminf(fmaxf(o23.y, 0.0f), HI);
                const int   i0 = (int)p;
                const float u  = fract_pos(p);
                const float g0 = rowp[i0], g1 = rowp[i0 + 1];
                acc3 = fmaf(fmaf(u, g1 - g0, g0), wk, acc3);
            }
        }

        orow[t0]       = acc0;
        orow[t0 + 256] = acc1;
        orow[t0 + 512] = acc2;
        if (it < 3 || tid < T_OUT - 3 * SPAN - 768)   // t0+768 < 4090
            orow[t0 + 768] = acc3;
    }
}

extern "C" void kernel_launch(void* const* d_in, const int* in_sizes, int n_in,
                              void* d_out, int out_size, void* d_ws, size_t ws_size,
                              hipStream_t stream) {
    const float* x        = (const float*)d_in[0];
    const float* weight   = (const float*)d_in[1];
    const float* offset_w = (const float*)d_in[2];
    const float* offset_b = (const float*)d_in[3];
    float* out = (float*)d_out;

    deform_dwconv1d_kernel<<<B_ * C_, BLOCK, 0, stream>>>(
        x, weight, offset_w, offset_b, out);
}

// Round 6
// 53.445 us; speedup vs baseline: 1.0625x; 1.0625x over previous
//
#include <hip/hip_runtime.h>

// Deformable depthwise conv1d (fp32), MI355X.
// Round 6: round-5 design (global-memory windows so the LDS pipe carries only
// the data-dependent bilinear gathers) + OOB fix: tail-iter window base is
// clamped to T-K so no lane reads past the row (previous round page-faulted
// on the last row of x).

constexpr int B_ = 8;
constexpr int C_ = 512;
constexpr int T_ = 4096;
constexpr int K_ = 7;
constexpr int T_OUT = T_ - K_ + 1;      // 4090
constexpr int BLOCK = 256;
constexpr int P_ = 16;                  // zero pad each side (>> max |offset|)
constexpr int ROWP = P_ + T_ + P_;      // 4128 floats = 16.5 KB
constexpr int SPAN = 2 * BLOCK;         // 512 t per outer iter

typedef float v2f __attribute__((ext_vector_type(2)));

__device__ __forceinline__ float fract_pos(float p) {
#if __has_builtin(__builtin_amdgcn_fractf)
    return __builtin_amdgcn_fractf(p);      // v_fract_f32 (p >= 0 here)
#else
    return p - floorf(p);
#endif
}

__device__ __forceinline__ float clamp01hi(float a, float hi) {
#if __has_builtin(__builtin_amdgcn_fmed3f)
    return __builtin_amdgcn_fmed3f(a, 0.0f, hi);   // v_med3_f32
#else
    return fminf(fmaxf(a, 0.0f), hi);
#endif
}

__global__ __launch_bounds__(BLOCK)
void deform_dwconv1d_kernel(const float* __restrict__ x,
                            const float* __restrict__ weight,
                            const float* __restrict__ offset_w,
                            const float* __restrict__ offset_b,
                            float* __restrict__ out)
{
    __shared__ float rowp[ROWP];

    const int bc  = blockIdx.x;        // b*C + c
    const int c   = bc & (C_ - 1);
    const int tid = threadIdx.x;

    // zero the pads
    if (tid < P_) {
        rowp[tid] = 0.0f;
        rowp[P_ + T_ + tid] = 0.0f;
    }

    // stage x[b,c,:] into rowp[P_ ..] (float4, coalesced)
    const float* xrow = x + (size_t)bc * T_;
    const float4* src = reinterpret_cast<const float4*>(xrow);
    float4* dst = reinterpret_cast<float4*>(rowp + P_);
    #pragma unroll
    for (int i = 0; i < T_ / 4 / BLOCK; ++i)   // 4 iters
        dst[tid + i * BLOCK] = src[tid + i * BLOCK];

    // per-channel weights: uniform addresses -> scalar loads / SGPRs
    float ow[K_ * K_];
    #pragma unroll
    for (int i = 0; i < K_ * K_; ++i) ow[i] = offset_w[c * K_ * K_ + i];
    float wgt[K_], obk[K_];
    #pragma unroll
    for (int k = 0; k < K_; ++k) {
        wgt[k] = weight[c * K_ + k];
        obk[k] = offset_b[c * K_ + k] + (float)k;   // fold +k into the bias
    }

    __syncthreads();

    float* orow = out + (size_t)bc * T_OUT;
    constexpr float HI = (float)(ROWP - 2);   // 4126: rowp[HI..HI+1] are pad zeros

    #pragma unroll
    for (int it = 0; it < 8; ++it) {
        const int tA = it * SPAN + tid;            // lane-stride-1, max 3839
        const int tB = tA + BLOCK;                 // lane-stride-1, max 4095
        // OOB guard: only the tail iter can have tB+6 > 4095. Clamp the
        // window base to T-K (=4089); affected lanes' outputs are discarded.
        const int tBw = (it == 7) ? min(tB, T_ - K_) : tB;

        // windows from GLOBAL (L1/L2-resident row; 1 base addr + imm offsets)
        float wA[K_], wB[K_];
        #pragma unroll
        for (int j = 0; j < K_; ++j) {
            wA[j] = xrow[tA + j];
            wB[j] = xrow[tBw + j];
        }

        const v2f tf = {(float)(tA + P_), (float)(tB + P_)};
        float accA = 0.0f, accB = 0.0f;

        #pragma unroll
        for (int k = 0; k < K_; ++k) {
            // packed offset conv; accumulator seeded with bias + k + t + P
            v2f o = tf + obk[k];
            #pragma unroll
            for (int j = 0; j < K_; ++j) {
                v2f w2 = {wA[j], wB[j]};
                v2f m2 = {ow[k * K_ + j], ow[k * K_ + j]};
                o = __builtin_elementwise_fma(w2, m2, o);
            }

            // clamp to padded range (v_med3), trunc/fract bilinear decompose
            const float pA = clamp01hi(o.x, HI);
            const float pB = clamp01hi(o.y, HI);
            const int   iA = (int)pA;              // p >= 0: trunc == floor
            const int   iB = (int)pB;
            const float uA = fract_pos(pA);
            const float uB = fract_pos(pB);

            // the ONLY LDS traffic: fused ds_read2_b32 gathers, ~stride-1 lanes
            const float g0A = rowp[iA], g1A = rowp[iA + 1];
            const float g0B = rowp[iB], g1B = rowp[iB + 1];

            const float sA = fmaf(uA, g1A - g0A, g0A);
            const float sB = fmaf(uB, g1B - g0B, g0B);
            accA = fmaf(sA, wgt[k], accA);
            accB = fmaf(sB, wgt[k], accB);
        }

        orow[tA] = accA;                            // tA <= 3839 always valid
        if (it < 7 || tid < T_OUT - 7 * SPAN - BLOCK)   // tB < 4090
            orow[tB] = accB;
    }
}

extern "C" void kernel_launch(void* const* d_in, const int* in_sizes, int n_in,
                              void* d_out, int out_size, void* d_ws, size_t ws_size,
                              hipStream_t stream) {
    const float* x        = (const float*)d_in[0];
    const float* weight   = (const float*)d_in[1];
    const float* offset_w = (const float*)d_in[2];
    const float* offset_b = (const float*)d_in[3];
    float* out = (float*)d_out;

    deform_dwconv1d_kernel<<<B_ * C_, BLOCK, 0, stream>>>(
        x, weight, offset_w, offset_b, out);
}